// Round 1
// baseline (1301.905 us; speedup 1.0000x reference)
//
#include <hip/hip_runtime.h>
#include <hip/hip_bf16.h>

#define HIDDEN 1024
#define FFN    2816
#define NEXP   8
#define NTOK   2048

#define BM 64
#define BN 64
#define BK 16

// Workspace layout (byte offsets):
//   [0,   32)                           counts: int[8]
//   [256, 256+8*2048*4)                 tok:    int[8][2048]
//   [65792, 65792+8*2048*4)             wts:    float[8][2048]
//   [131584, 131584+4096*2816*2)        hbuf:   bf16[4096][2816]   (~23 MB)

// ---------------- Router: logits -> softmax -> top2 -> per-expert lists ---------
__global__ void __launch_bounds__(64)
router_kernel(const float* __restrict__ x, const float* __restrict__ Wgate,
              int* __restrict__ counts, int* __restrict__ tok,
              float* __restrict__ wts)
{
    int t = blockIdx.x;
    int lane = threadIdx.x;
    float acc[NEXP];
#pragma unroll
    for (int e = 0; e < NEXP; e++) acc[e] = 0.f;
    const float* xrow = x + (size_t)t * HIDDEN;
    for (int h = lane; h < HIDDEN; h += 64) {
        float xv = xrow[h];
#pragma unroll
        for (int e = 0; e < NEXP; e++) acc[e] += xv * Wgate[e * HIDDEN + h];
    }
#pragma unroll
    for (int off = 32; off > 0; off >>= 1) {
#pragma unroll
        for (int e = 0; e < NEXP; e++) acc[e] += __shfl_down(acc[e], off);
    }
    if (lane == 0) {
        float mx = acc[0];
#pragma unroll
        for (int e = 1; e < NEXP; e++) mx = fmaxf(mx, acc[e]);
        float p[NEXP];
#pragma unroll
        for (int e = 0; e < NEXP; e++) p[e] = __expf(acc[e] - mx);
        // top-1 (first occurrence on tie, matches lax.top_k)
        int i0 = 0; float p0 = p[0];
#pragma unroll
        for (int e = 1; e < NEXP; e++) if (p[e] > p0) { p0 = p[e]; i0 = e; }
        int i1 = -1; float p1 = -1.f;
#pragma unroll
        for (int e = 0; e < NEXP; e++) {
            if (e == i0) continue;
            if (p[e] > p1) { p1 = p[e]; i1 = e; }
        }
        // softmax denominator cancels in the renormalization: w0 = p0/(p0+p1)
        float inv = 1.f / (p0 + p1);
        float w0 = p0 * inv, w1 = p1 * inv;
        int s0 = atomicAdd(&counts[i0], 1);
        tok[i0 * NTOK + s0] = t; wts[i0 * NTOK + s0] = w0;
        int s1 = atomicAdd(&counts[i1], 1);
        tok[i1 * NTOK + s1] = t; wts[i1 * NTOK + s1] = w1;
    }
}

// ---------------- Stage A: h = silu(x Wg^T) * (x Wu^T), gathered per expert ----
__global__ void __launch_bounds__(256)
ffn1_kernel(const float* __restrict__ x, const float* __restrict__ Wg,
            const float* __restrict__ Wu, const int* __restrict__ counts,
            const int* __restrict__ tok, __hip_bfloat16* __restrict__ hbuf)
{
    int e = blockIdx.z;
    int cnt = counts[e];
    int row0 = blockIdx.y * BM;
    if (row0 >= cnt) return;
    int off_e = 0;
    for (int i = 0; i < e; i++) off_e += counts[i];
    int f0 = blockIdx.x * BN;

    __shared__ float As[BK][BM + 4];
    __shared__ float Bgs[BK][BN + 4];
    __shared__ float Bus[BK][BN + 4];
    __shared__ int   stok[BM];

    int tid = threadIdx.x;
    if (tid < BM) {
        int r = row0 + tid;
        stok[tid] = tok[e * NTOK + min(r, cnt - 1)];
    }
    __syncthreads();

    int lr = tid >> 2;            // 0..63: row within tile for global loads
    int lk = (tid & 3) * 4;       // k sub-offset 0,4,8,12
    int tx = tid & 15, ty = tid >> 4;

    float cg[4][4] = {{0}}, cu[4][4] = {{0}};

    const float* Wge = Wg + (size_t)e * FFN * HIDDEN;
    const float* Wue = Wu + (size_t)e * FFN * HIDDEN;
    const float* arow = x + (size_t)stok[lr] * HIDDEN;

    for (int k0 = 0; k0 < HIDDEN; k0 += BK) {
        float4 av = *(const float4*)(arow + k0 + lk);
        float4 bg = *(const float4*)(Wge + (size_t)(f0 + lr) * HIDDEN + k0 + lk);
        float4 bu = *(const float4*)(Wue + (size_t)(f0 + lr) * HIDDEN + k0 + lk);
        __syncthreads();
        As[lk + 0][lr] = av.x; As[lk + 1][lr] = av.y;
        As[lk + 2][lr] = av.z; As[lk + 3][lr] = av.w;
        Bgs[lk + 0][lr] = bg.x; Bgs[lk + 1][lr] = bg.y;
        Bgs[lk + 2][lr] = bg.z; Bgs[lk + 3][lr] = bg.w;
        Bus[lk + 0][lr] = bu.x; Bus[lk + 1][lr] = bu.y;
        Bus[lk + 2][lr] = bu.z; Bus[lk + 3][lr] = bu.w;
        __syncthreads();
#pragma unroll
        for (int k = 0; k < BK; k++) {
            float a[4], g[4], u[4];
#pragma unroll
            for (int j = 0; j < 4; j++) {
                a[j] = As[k][ty * 4 + j];
                g[j] = Bgs[k][tx * 4 + j];
                u[j] = Bus[k][tx * 4 + j];
            }
#pragma unroll
            for (int i = 0; i < 4; i++)
#pragma unroll
                for (int j = 0; j < 4; j++) {
                    cg[i][j] += a[i] * g[j];
                    cu[i][j] += a[i] * u[j];
                }
        }
    }

#pragma unroll
    for (int i = 0; i < 4; i++) {
        int grow = row0 + ty * 4 + i;
        if (grow < cnt) {
            __hip_bfloat16* hrow = hbuf + (size_t)(off_e + grow) * FFN + f0;
#pragma unroll
            for (int j = 0; j < 4; j++) {
                float g = cg[i][j], u = cu[i][j];
                float h = g / (1.f + __expf(-g)) * u;   // silu(g)*u
                hrow[tx * 4 + j] = __float2bfloat16(h);
            }
        }
    }
}

// ---------------- Stage B: out[t,:] += w * (h Wd^T) ----------------------------
__global__ void __launch_bounds__(256)
ffn2_kernel(const __hip_bfloat16* __restrict__ hbuf, const float* __restrict__ Wd,
            const int* __restrict__ counts, const int* __restrict__ tok,
            const float* __restrict__ wts, float* __restrict__ out)
{
    int e = blockIdx.z;
    int cnt = counts[e];
    int row0 = blockIdx.y * BM;
    if (row0 >= cnt) return;
    int off_e = 0;
    for (int i = 0; i < e; i++) off_e += counts[i];
    int h0 = blockIdx.x * BN;

    __shared__ float As[BK][BM + 4];
    __shared__ float Bs[BK][BN + 4];
    __shared__ int   stok[BM];
    __shared__ float swt[BM];

    int tid = threadIdx.x;
    if (tid < BM) {
        int rc = min(row0 + tid, cnt - 1);
        stok[tid] = tok[e * NTOK + rc];
        swt[tid] = wts[e * NTOK + rc];
    }
    __syncthreads();

    int lr = tid >> 2;
    int lk = (tid & 3) * 4;
    int tx = tid & 15, ty = tid >> 4;

    float c[4][4] = {{0}};

    const float* Wde = Wd + (size_t)e * HIDDEN * FFN;
    int ar = min(row0 + lr, cnt - 1);   // clamp: rows past cnt must not read OOB
    const __hip_bfloat16* arow = hbuf + (size_t)(off_e + ar) * FFN;

    for (int k0 = 0; k0 < FFN; k0 += BK) {
        uint2 araw = *(const uint2*)(arow + k0 + lk);        // 4 bf16
        float4 bv = *(const float4*)(Wde + (size_t)(h0 + lr) * FFN + k0 + lk);
        __syncthreads();
        As[lk + 0][lr] = __uint_as_float((araw.x & 0xffffu) << 16);
        As[lk + 1][lr] = __uint_as_float(araw.x & 0xffff0000u);
        As[lk + 2][lr] = __uint_as_float((araw.y & 0xffffu) << 16);
        As[lk + 3][lr] = __uint_as_float(araw.y & 0xffff0000u);
        Bs[lk + 0][lr] = bv.x; Bs[lk + 1][lr] = bv.y;
        Bs[lk + 2][lr] = bv.z; Bs[lk + 3][lr] = bv.w;
        __syncthreads();
#pragma unroll
        for (int k = 0; k < BK; k++) {
            float a[4], b[4];
#pragma unroll
            for (int j = 0; j < 4; j++) {
                a[j] = As[k][ty * 4 + j];
                b[j] = Bs[k][tx * 4 + j];
            }
#pragma unroll
            for (int i = 0; i < 4; i++)
#pragma unroll
                for (int j = 0; j < 4; j++)
                    c[i][j] += a[i] * b[j];
        }
    }

#pragma unroll
    for (int i = 0; i < 4; i++) {
        int r = ty * 4 + i;
        int grow = row0 + r;
        if (grow < cnt) {
            int t = stok[r];
            float w = swt[r];
            float* orow = out + (size_t)t * HIDDEN + h0;
#pragma unroll
            for (int j = 0; j < 4; j++)
                atomicAdd(&orow[tx * 4 + j], w * c[i][j]);
        }
    }
}

extern "C" void kernel_launch(void* const* d_in, const int* in_sizes, int n_in,
                              void* d_out, int out_size, void* d_ws, size_t ws_size,
                              hipStream_t stream) {
    const float* x     = (const float*)d_in[0];
    const float* Wgate = (const float*)d_in[1];
    const float* Wg    = (const float*)d_in[2];
    const float* Wu    = (const float*)d_in[3];
    const float* Wd    = (const float*)d_in[4];
    float* out = (float*)d_out;

    char* ws = (char*)d_ws;
    int*   counts = (int*)ws;
    int*   tok    = (int*)(ws + 256);
    float* wts    = (float*)(ws + 256 + NEXP * NTOK * 4);
    __hip_bfloat16* hbuf = (__hip_bfloat16*)(ws + 256 + 2 * NEXP * NTOK * 4);

    hipMemsetAsync(counts, 0, 256, stream);
    hipMemsetAsync(out, 0, (size_t)out_size * sizeof(float), stream);

    router_kernel<<<NTOK, 64, 0, stream>>>(x, Wgate, counts, tok, wts);

    dim3 g1(FFN / BN, NTOK / BM, NEXP);      // 44 x 32 x 8, early-exit on count
    ffn1_kernel<<<g1, 256, 0, stream>>>(x, Wg, Wu, counts, tok, hbuf);

    dim3 g2(HIDDEN / BN, NTOK / BM, NEXP);   // 16 x 32 x 8
    ffn2_kernel<<<g2, 256, 0, stream>>>(hbuf, Wd, counts, tok, wts, out);
}

// Round 2
// 814.518 us; speedup vs baseline: 1.5984x; 1.5984x over previous
//
#include <hip/hip_runtime.h>
#include <hip/hip_bf16.h>

#define HIDDEN 1024
#define FFN    2816
#define NEXP   8
#define NTOK   2048

typedef __attribute__((ext_vector_type(8))) short short8;   // 8 bf16 = 4 VGPRs
typedef __attribute__((ext_vector_type(4))) float f32x4;

static __device__ inline short f2bf(float f) {
    __hip_bfloat16 h = __float2bfloat16(f);
    return *(short*)&h;
}

// ---------------- Router: logits -> softmax -> top2 -> per-expert lists ---------
__global__ void __launch_bounds__(64)
router_kernel(const float* __restrict__ x, const float* __restrict__ Wgate,
              int* __restrict__ counts, int* __restrict__ tok,
              float* __restrict__ wts)
{
    int t = blockIdx.x;
    int lane = threadIdx.x;
    float acc[NEXP];
#pragma unroll
    for (int e = 0; e < NEXP; e++) acc[e] = 0.f;
    const float* xrow = x + (size_t)t * HIDDEN;
    for (int h = lane; h < HIDDEN; h += 64) {
        float xv = xrow[h];
#pragma unroll
        for (int e = 0; e < NEXP; e++) acc[e] += xv * Wgate[e * HIDDEN + h];
    }
#pragma unroll
    for (int off = 32; off > 0; off >>= 1) {
#pragma unroll
        for (int e = 0; e < NEXP; e++) acc[e] += __shfl_down(acc[e], off);
    }
    if (lane == 0) {
        float mx = acc[0];
#pragma unroll
        for (int e = 1; e < NEXP; e++) mx = fmaxf(mx, acc[e]);
        float p[NEXP];
#pragma unroll
        for (int e = 0; e < NEXP; e++) p[e] = __expf(acc[e] - mx);
        int i0 = 0; float p0 = p[0];
#pragma unroll
        for (int e = 1; e < NEXP; e++) if (p[e] > p0) { p0 = p[e]; i0 = e; }
        int i1 = -1; float p1 = -1.f;
#pragma unroll
        for (int e = 0; e < NEXP; e++) {
            if (e == i0) continue;
            if (p[e] > p1) { p1 = p[e]; i1 = e; }
        }
        float inv = 1.f / (p0 + p1);
        float w0 = p0 * inv, w1 = p1 * inv;
        int s0 = atomicAdd(&counts[i0], 1);
        tok[i0 * NTOK + s0] = t; wts[i0 * NTOK + s0] = w0;
        int s1 = atomicAdd(&counts[i1], 1);
        tok[i1 * NTOK + s1] = t; wts[i1 * NTOK + s1] = w1;
    }
}

// ---------------- Stage A: h = silu(x Wg^T) * (x Wu^T), MFMA bf16 --------------
// tile: 128 tokens x 64 ffn, BK=32.  4 waves, each 64x32 (4x2 mfma tiles).
#define LDW 40   // LDS row stride in shorts: 80 B — 16B-aligned rows, 2-way bank alias (free)
__global__ void __launch_bounds__(256, 2)
ffn1_mfma(const float* __restrict__ x, const float* __restrict__ Wg,
          const float* __restrict__ Wu, const int* __restrict__ counts,
          const int* __restrict__ tok, __hip_bfloat16* __restrict__ hbuf)
{
    int e = blockIdx.z;
    int cnt = counts[e];
    int row0 = blockIdx.x * 128;
    if (row0 >= cnt) return;
    int off_e = 0;
#pragma unroll
    for (int i = 0; i < NEXP; i++) if (i < e) off_e += counts[i];
    int f0 = blockIdx.y * 64;

    __shared__ short Xs[128][LDW];
    __shared__ short Gs[64][LDW];
    __shared__ short Us[64][LDW];
    __shared__ int   stok[128];

    int tid = threadIdx.x;
    if (tid < 128) stok[tid] = tok[e * NTOK + min(row0 + tid, cnt - 1)];
    __syncthreads();

    int lane = tid & 63;
    int w    = tid >> 6;
    int wm   = (w & 1) * 64;        // token sub-tile
    int wn   = (w >> 1) * 32;       // ffn sub-tile
    int l15  = lane & 15;
    int lq   = lane >> 4;           // 0..3

    f32x4 cg[4][2], cu[4][2];
#pragma unroll
    for (int i = 0; i < 4; i++)
#pragma unroll
        for (int j = 0; j < 2; j++) { cg[i][j] = (f32x4)0.f; cu[i][j] = (f32x4)0.f; }

    const float* Wge = Wg + (size_t)e * FFN * HIDDEN;
    const float* Wue = Wu + (size_t)e * FFN * HIDDEN;

    // per-thread staging slots
    int xr[4], xc[4];
    const float* xp[4];
#pragma unroll
    for (int i = 0; i < 4; i++) {
        int idx = tid + 256 * i;
        xr[i] = idx >> 3; xc[i] = (idx & 7) * 4;
        xp[i] = x + (size_t)stok[xr[i]] * HIDDEN + xc[i];
    }
    int wr[2], wc[2];
    const float* gp[2]; const float* up[2];
#pragma unroll
    for (int i = 0; i < 2; i++) {
        int idx = tid + 256 * i;
        wr[i] = idx >> 3; wc[i] = (idx & 7) * 4;
        gp[i] = Wge + (size_t)(f0 + wr[i]) * HIDDEN + wc[i];
        up[i] = Wue + (size_t)(f0 + wr[i]) * HIDDEN + wc[i];
    }

    float4 xa[4], ga[2], ua[2];
#pragma unroll
    for (int i = 0; i < 4; i++) xa[i] = *(const float4*)(xp[i]);
#pragma unroll
    for (int i = 0; i < 2; i++) { ga[i] = *(const float4*)(gp[i]); ua[i] = *(const float4*)(up[i]); }

    for (int k0 = 0; k0 < HIDDEN; k0 += 32) {
        __syncthreads();   // previous iter's LDS reads complete
#pragma unroll
        for (int i = 0; i < 4; i++) {
            short* d = &Xs[xr[i]][xc[i]];
            d[0] = f2bf(xa[i].x); d[1] = f2bf(xa[i].y);
            d[2] = f2bf(xa[i].z); d[3] = f2bf(xa[i].w);
        }
#pragma unroll
        for (int i = 0; i < 2; i++) {
            short* d = &Gs[wr[i]][wc[i]];
            d[0] = f2bf(ga[i].x); d[1] = f2bf(ga[i].y);
            d[2] = f2bf(ga[i].z); d[3] = f2bf(ga[i].w);
            short* d2 = &Us[wr[i]][wc[i]];
            d2[0] = f2bf(ua[i].x); d2[1] = f2bf(ua[i].y);
            d2[2] = f2bf(ua[i].z); d2[3] = f2bf(ua[i].w);
        }
        __syncthreads();
        if (k0 + 32 < HIDDEN) {   // prefetch next slab; latency hidden by MFMAs
            int kn = k0 + 32;
#pragma unroll
            for (int i = 0; i < 4; i++) xa[i] = *(const float4*)(xp[i] + kn);
#pragma unroll
            for (int i = 0; i < 2; i++) { ga[i] = *(const float4*)(gp[i] + kn); ua[i] = *(const float4*)(up[i] + kn); }
        }
        short8 af[4], bg[2], bu[2];
#pragma unroll
        for (int mi = 0; mi < 4; mi++) af[mi] = *(const short8*)&Xs[wm + mi * 16 + l15][lq * 8];
#pragma unroll
        for (int ni = 0; ni < 2; ni++) {
            bg[ni] = *(const short8*)&Gs[wn + ni * 16 + l15][lq * 8];
            bu[ni] = *(const short8*)&Us[wn + ni * 16 + l15][lq * 8];
        }
#pragma unroll
        for (int mi = 0; mi < 4; mi++)
#pragma unroll
            for (int ni = 0; ni < 2; ni++) {
                cg[mi][ni] = __builtin_amdgcn_mfma_f32_16x16x32_bf16(af[mi], bg[ni], cg[mi][ni], 0, 0, 0);
                cu[mi][ni] = __builtin_amdgcn_mfma_f32_16x16x32_bf16(af[mi], bu[ni], cu[mi][ni], 0, 0, 0);
            }
    }

    // epilogue: silu(g)*u -> bf16 hbuf.  C/D: col=lane&15, row=lq*4+reg
#pragma unroll
    for (int mi = 0; mi < 4; mi++)
#pragma unroll
        for (int r = 0; r < 4; r++) {
            int row = wm + mi * 16 + lq * 4 + r;
            int grow = row0 + row;
            if (grow < cnt) {
                __hip_bfloat16* hrow = hbuf + (size_t)(off_e + grow) * FFN + f0 + wn;
#pragma unroll
                for (int ni = 0; ni < 2; ni++) {
                    float g = cg[mi][ni][r], u = cu[mi][ni][r];
                    float h = g / (1.f + __expf(-g)) * u;
                    hrow[ni * 16 + l15] = __float2bfloat16(h);
                }
            }
        }
}

// ---------------- Stage B: out[t,:] += w * (h Wd^T), MFMA bf16 -----------------
__global__ void __launch_bounds__(256, 2)
ffn2_mfma(const __hip_bfloat16* __restrict__ hbuf, const float* __restrict__ Wd,
          const int* __restrict__ counts, const int* __restrict__ tok,
          const float* __restrict__ wts, float* __restrict__ out)
{
    int e = blockIdx.z;
    int cnt = counts[e];
    int row0 = blockIdx.x * 128;
    if (row0 >= cnt) return;
    int off_e = 0;
#pragma unroll
    for (int i = 0; i < NEXP; i++) if (i < e) off_e += counts[i];
    int h0 = blockIdx.y * 64;

    __shared__ short Hs[128][LDW];
    __shared__ short Ds[64][LDW];
    __shared__ int   stok[128];
    __shared__ float swt[128];

    int tid = threadIdx.x;
    if (tid < 128) {
        int rc = min(row0 + tid, cnt - 1);
        stok[tid] = tok[e * NTOK + rc];
        swt[tid]  = wts[e * NTOK + rc];
    }
    __syncthreads();

    int lane = tid & 63;
    int w    = tid >> 6;
    int wm   = (w & 1) * 64;
    int wn   = (w >> 1) * 32;
    int l15  = lane & 15;
    int lq   = lane >> 4;

    f32x4 c[4][2];
#pragma unroll
    for (int i = 0; i < 4; i++)
#pragma unroll
        for (int j = 0; j < 2; j++) c[i][j] = (f32x4)0.f;

    const float* Wde = Wd + (size_t)e * HIDDEN * FFN;

    // A: bf16 direct, 8 bf16 (16B) per load. 128 rows x 4 loads => 2/thread
    int hr[2], hc[2];
    const short* hp[2];
#pragma unroll
    for (int i = 0; i < 2; i++) {
        int idx = tid + 256 * i;
        hr[i] = idx >> 2; hc[i] = (idx & 3) * 8;
        int ar = min(row0 + hr[i], cnt - 1);
        hp[i] = (const short*)(hbuf + (size_t)(off_e + ar) * FFN + hc[i]);
    }
    int dr[2], dc[2];
    const float* dp[2];
#pragma unroll
    for (int i = 0; i < 2; i++) {
        int idx = tid + 256 * i;
        dr[i] = idx >> 3; dc[i] = (idx & 7) * 4;
        dp[i] = Wde + (size_t)(h0 + dr[i]) * FFN + dc[i];
    }

    short8 ha[2]; float4 da[2];
#pragma unroll
    for (int i = 0; i < 2; i++) { ha[i] = *(const short8*)(hp[i]); da[i] = *(const float4*)(dp[i]); }

    for (int k0 = 0; k0 < FFN; k0 += 32) {
        __syncthreads();
#pragma unroll
        for (int i = 0; i < 2; i++) {
            *(short8*)&Hs[hr[i]][hc[i]] = ha[i];
            short* d = &Ds[dr[i]][dc[i]];
            d[0] = f2bf(da[i].x); d[1] = f2bf(da[i].y);
            d[2] = f2bf(da[i].z); d[3] = f2bf(da[i].w);
        }
        __syncthreads();
        if (k0 + 32 < FFN) {
            int kn = k0 + 32;
#pragma unroll
            for (int i = 0; i < 2; i++) { ha[i] = *(const short8*)(hp[i] + kn); da[i] = *(const float4*)(dp[i] + kn); }
        }
        short8 af[4], bf[2];
#pragma unroll
        for (int mi = 0; mi < 4; mi++) af[mi] = *(const short8*)&Hs[wm + mi * 16 + l15][lq * 8];
#pragma unroll
        for (int ni = 0; ni < 2; ni++) bf[ni] = *(const short8*)&Ds[wn + ni * 16 + l15][lq * 8];
#pragma unroll
        for (int mi = 0; mi < 4; mi++)
#pragma unroll
            for (int ni = 0; ni < 2; ni++)
                c[mi][ni] = __builtin_amdgcn_mfma_f32_16x16x32_bf16(af[mi], bf[ni], c[mi][ni], 0, 0, 0);
    }

#pragma unroll
    for (int mi = 0; mi < 4; mi++)
#pragma unroll
        for (int r = 0; r < 4; r++) {
            int row = wm + mi * 16 + lq * 4 + r;
            int grow = row0 + row;
            if (grow < cnt) {
                int t = stok[row];
                float wgt = swt[row];
                float* orow = out + (size_t)t * HIDDEN + h0 + wn;
#pragma unroll
                for (int ni = 0; ni < 2; ni++)
                    atomicAdd(&orow[ni * 16 + l15], wgt * c[mi][ni][r]);
            }
        }
}

extern "C" void kernel_launch(void* const* d_in, const int* in_sizes, int n_in,
                              void* d_out, int out_size, void* d_ws, size_t ws_size,
                              hipStream_t stream) {
    const float* x     = (const float*)d_in[0];
    const float* Wgate = (const float*)d_in[1];
    const float* Wg    = (const float*)d_in[2];
    const float* Wu    = (const float*)d_in[3];
    const float* Wd    = (const float*)d_in[4];
    float* out = (float*)d_out;

    char* ws = (char*)d_ws;
    int*   counts = (int*)ws;
    int*   tok    = (int*)(ws + 256);
    float* wts    = (float*)(ws + 256 + NEXP * NTOK * 4);
    __hip_bfloat16* hbuf = (__hip_bfloat16*)(ws + 256 + 2 * NEXP * NTOK * 4);

    hipMemsetAsync(counts, 0, 256, stream);
    hipMemsetAsync(out, 0, (size_t)out_size * sizeof(float), stream);

    router_kernel<<<NTOK, 64, 0, stream>>>(x, Wgate, counts, tok, wts);

    dim3 g1(NTOK / 128, FFN / 64, NEXP);     // token-tile fastest: weight-slab L2 reuse
    ffn1_mfma<<<g1, 256, 0, stream>>>(x, Wg, Wu, counts, tok, hbuf);

    dim3 g2(NTOK / 128, HIDDEN / 64, NEXP);
    ffn2_mfma<<<g2, 256, 0, stream>>>(hbuf, Wd, counts, tok, wts, out);
}

// Round 3
// 694.505 us; speedup vs baseline: 1.8746x; 1.1728x over previous
//
#include <hip/hip_runtime.h>
#include <hip/hip_bf16.h>

#define HIDDEN 1024
#define FFN    2816
#define NEXP   8
#define NTOK   2048

typedef __attribute__((ext_vector_type(8))) short short8;   // 8 bf16 = 4 VGPRs
typedef __attribute__((ext_vector_type(4))) float f32x4;

static __device__ __forceinline__ short f2bf(float f) {
    __hip_bfloat16 h = __float2bfloat16(f);
    return *(short*)&h;
}

// async 16-B global->LDS DMA (lane i lands at ldsbase + i*16)
static __device__ __forceinline__ void gl_lds16(const short* g, short* l) {
    __builtin_amdgcn_global_load_lds(
        (const __attribute__((address_space(1))) void*)g,
        (__attribute__((address_space(3))) void*)l, 16, 0, 0);
}

// ---------------- Router: logits -> softmax -> top2 -> per-expert lists ---------
__global__ void __launch_bounds__(64)
router_kernel(const float* __restrict__ x, const float* __restrict__ Wgate,
              int* __restrict__ counts, int* __restrict__ tok,
              float* __restrict__ wts)
{
    int t = blockIdx.x;
    int lane = threadIdx.x;
    float acc[NEXP];
#pragma unroll
    for (int e = 0; e < NEXP; e++) acc[e] = 0.f;
    const float* xrow = x + (size_t)t * HIDDEN;
    for (int h = lane; h < HIDDEN; h += 64) {
        float xv = xrow[h];
#pragma unroll
        for (int e = 0; e < NEXP; e++) acc[e] += xv * Wgate[e * HIDDEN + h];
    }
#pragma unroll
    for (int off = 32; off > 0; off >>= 1) {
#pragma unroll
        for (int e = 0; e < NEXP; e++) acc[e] += __shfl_down(acc[e], off);
    }
    if (lane == 0) {
        float mx = acc[0];
#pragma unroll
        for (int e = 1; e < NEXP; e++) mx = fmaxf(mx, acc[e]);
        float p[NEXP];
#pragma unroll
        for (int e = 0; e < NEXP; e++) p[e] = __expf(acc[e] - mx);
        int i0 = 0; float p0 = p[0];
#pragma unroll
        for (int e = 1; e < NEXP; e++) if (p[e] > p0) { p0 = p[e]; i0 = e; }
        int i1 = -1; float p1 = -1.f;
#pragma unroll
        for (int e = 0; e < NEXP; e++) {
            if (e == i0) continue;
            if (p[e] > p1) { p1 = p[e]; i1 = e; }
        }
        float inv = 1.f / (p0 + p1);
        float w0 = p0 * inv, w1 = p1 * inv;
        int s0 = atomicAdd(&counts[i0], 1);
        tok[i0 * NTOK + s0] = t; wts[i0 * NTOK + s0] = w0;
        int s1 = atomicAdd(&counts[i1], 1);
        tok[i1 * NTOK + s1] = t; wts[i1 * NTOK + s1] = w1;
    }
}

// ---------------- fp32 -> bf16 pre-pass over x, Wg, Wu, Wd ---------------------
__global__ void __launch_bounds__(256)
cvt_all(const float* __restrict__ s0, const float* __restrict__ s1,
        const float* __restrict__ s2, const float* __restrict__ s3,
        short* __restrict__ d0, short* __restrict__ d1,
        short* __restrict__ d2, short* __restrict__ d3)
{
    const long long n0 = (long long)(NTOK * HIDDEN) / 8;        // 262144 groups of 8
    const long long nw = (long long)NEXP * FFN * HIDDEN / 8;    // 2883584
    long long tot = n0 + 3 * nw;
    for (long long i = (long long)blockIdx.x * 256 + threadIdx.x; i < tot;
         i += (long long)gridDim.x * 256) {
        const float* s; short* d; long long r;
        if (i < n0)               { s = s0; d = d0; r = i; }
        else if (i < n0 + nw)     { s = s1; d = d1; r = i - n0; }
        else if (i < n0 + 2 * nw) { s = s2; d = d2; r = i - n0 - nw; }
        else                      { s = s3; d = d3; r = i - n0 - 2 * nw; }
        float4 a = ((const float4*)s)[2 * r];
        float4 b = ((const float4*)s)[2 * r + 1];
        short8 o;
        o[0] = f2bf(a.x); o[1] = f2bf(a.y); o[2] = f2bf(a.z); o[3] = f2bf(a.w);
        o[4] = f2bf(b.x); o[5] = f2bf(b.y); o[6] = f2bf(b.z); o[7] = f2bf(b.w);
        *(short8*)(d + 8 * r) = o;
    }
}

// ---------------- Stage A (primary): 128x128 tile, async LDS staging -----------
// LDS rows: 32 bf16 = 64 B, unpadded (DMA constraint). XOR chunk swizzle
// (c -> c ^ ((row>>1)&3)) makes ds_read_b128 a free 2-way bank alias.
__global__ void __launch_bounds__(256, 2)
ffn1_v3(const short* __restrict__ xbf, const short* __restrict__ Wgbf,
        const short* __restrict__ Wubf, const int* __restrict__ counts,
        const int* __restrict__ tok, short* __restrict__ hbuf)
{
    int e = blockIdx.z;
    int cnt = counts[e];
    int row0 = blockIdx.x * 128;
    if (row0 >= cnt) return;
    int off_e = 0;
#pragma unroll
    for (int i = 0; i < NEXP; i++) if (i < e) off_e += counts[i];
    int f0 = blockIdx.y * 128;

    __shared__ short Xs[128 * 32];
    __shared__ short Gs[128 * 32];
    __shared__ short Us[128 * 32];
    __shared__ int   stok[128];

    int tid = threadIdx.x;
    if (tid < 128) stok[tid] = tok[e * NTOK + min(row0 + tid, cnt - 1)];
    __syncthreads();

    int lane = tid & 63, w = tid >> 6;
    int l15 = lane & 15, lq = lane >> 4;
    int wm = (w & 1) * 64, wn = (w >> 1) * 64;

    // staging: wave w fills rows [w*32, w*32+32) of each tile, 2 DMA instrs each
    int prow   = lane >> 2;                           // row within 16-row group
    int gchunk = (lane & 3) ^ ((lane >> 3) & 3);      // swizzled source chunk
    const short* xsrc[2]; const short* gsrc[2]; const short* usrc[2];
    short* xdst[2]; short* gdst[2]; short* udst[2];
#pragma unroll
    for (int j = 0; j < 2; j++) {
        int rbase = w * 32 + j * 16;
        int r = rbase + prow;
        xsrc[j] = xbf + (size_t)stok[r] * HIDDEN + gchunk * 8;
        gsrc[j] = Wgbf + (size_t)e * FFN * HIDDEN + (size_t)(f0 + r) * HIDDEN + gchunk * 8;
        usrc[j] = Wubf + (size_t)e * FFN * HIDDEN + (size_t)(f0 + r) * HIDDEN + gchunk * 8;
        xdst[j] = &Xs[rbase * 32];
        gdst[j] = &Gs[rbase * 32];
        udst[j] = &Us[rbase * 32];
    }

    // fragment LDS element offsets (row*32 + swizzled chunk*8)
    int aoff[4], boff[4];
#pragma unroll
    for (int mi = 0; mi < 4; mi++) {
        int r = wm + mi * 16 + l15;
        aoff[mi] = r * 32 + (lq ^ ((r >> 1) & 3)) * 8;
    }
#pragma unroll
    for (int ni = 0; ni < 4; ni++) {
        int r = wn + ni * 16 + l15;
        boff[ni] = r * 32 + (lq ^ ((r >> 1) & 3)) * 8;
    }

    f32x4 cg[4][4], cu[4][4];
#pragma unroll
    for (int i = 0; i < 4; i++)
#pragma unroll
        for (int j = 0; j < 4; j++) { cg[i][j] = (f32x4)0.f; cu[i][j] = (f32x4)0.f; }

    for (int k0 = 0; k0 < HIDDEN; k0 += 32) {
#pragma unroll
        for (int j = 0; j < 2; j++) {
            gl_lds16(xsrc[j] + k0, xdst[j]);
            gl_lds16(gsrc[j] + k0, gdst[j]);
            gl_lds16(usrc[j] + k0, udst[j]);
        }
        __syncthreads();          // drains the DMA (vmcnt) + publishes LDS
        short8 af[4], bg[4], bu[4];
#pragma unroll
        for (int mi = 0; mi < 4; mi++) af[mi] = *(const short8*)&Xs[aoff[mi]];
#pragma unroll
        for (int ni = 0; ni < 4; ni++) {
            bg[ni] = *(const short8*)&Gs[boff[ni]];
            bu[ni] = *(const short8*)&Us[boff[ni]];
        }
#pragma unroll
        for (int mi = 0; mi < 4; mi++)
#pragma unroll
            for (int ni = 0; ni < 4; ni++) {
                cg[mi][ni] = __builtin_amdgcn_mfma_f32_16x16x32_bf16(af[mi], bg[ni], cg[mi][ni], 0, 0, 0);
                cu[mi][ni] = __builtin_amdgcn_mfma_f32_16x16x32_bf16(af[mi], bu[ni], cu[mi][ni], 0, 0, 0);
            }
        __syncthreads();          // readers done before next stage overwrites
    }

    // epilogue: silu(g)*u -> bf16 hbuf.  C/D: col=lane&15, row=lq*4+reg
#pragma unroll
    for (int mi = 0; mi < 4; mi++)
#pragma unroll
        for (int r = 0; r < 4; r++) {
            int row = wm + mi * 16 + lq * 4 + r;
            int grow = row0 + row;
            if (grow < cnt) {
                short* hrow = hbuf + (size_t)(off_e + grow) * FFN + f0 + wn;
#pragma unroll
                for (int ni = 0; ni < 4; ni++) {
                    float g = cg[mi][ni][r], u = cu[mi][ni][r];
                    float h = g / (1.f + __expf(-g)) * u;
                    hrow[ni * 16 + l15] = f2bf(h);
                }
            }
        }
}

// ---------------- Stage B (primary): 128x128 tile, K split in 2 ----------------
__global__ void __launch_bounds__(256, 2)
ffn2_v3(const short* __restrict__ hbuf, const short* __restrict__ Wdbf,
        const int* __restrict__ counts, const int* __restrict__ tok,
        const float* __restrict__ wts, float* __restrict__ out)
{
    int e = blockIdx.z;
    int cnt = counts[e];
    int row0 = blockIdx.x * 128;
    if (row0 >= cnt) return;
    int off_e = 0;
#pragma unroll
    for (int i = 0; i < NEXP; i++) if (i < e) off_e += counts[i];
    int h0    = (blockIdx.y >> 1) * 128;
    int kbase = (blockIdx.y & 1) * (FFN / 2);

    __shared__ short Hs[128 * 32];
    __shared__ short Ds[128 * 32];
    __shared__ int   stok[128];
    __shared__ float swt[128];

    int tid = threadIdx.x;
    if (tid < 128) {
        int rc = min(row0 + tid, cnt - 1);
        stok[tid] = tok[e * NTOK + rc];
        swt[tid]  = wts[e * NTOK + rc];
    }
    __syncthreads();

    int lane = tid & 63, w = tid >> 6;
    int l15 = lane & 15, lq = lane >> 4;
    int wm = (w & 1) * 64, wn = (w >> 1) * 64;

    int prow   = lane >> 2;
    int gchunk = (lane & 3) ^ ((lane >> 3) & 3);
    const short* hsrc[2]; const short* dsrc[2];
    short* hdst[2]; short* ddst[2];
#pragma unroll
    for (int j = 0; j < 2; j++) {
        int rbase = w * 32 + j * 16;
        int r = rbase + prow;
        hsrc[j] = hbuf + (size_t)(off_e + min(row0 + r, cnt - 1)) * FFN + kbase + gchunk * 8;
        dsrc[j] = Wdbf + (size_t)e * HIDDEN * FFN + (size_t)(h0 + r) * FFN + kbase + gchunk * 8;
        hdst[j] = &Hs[rbase * 32];
        ddst[j] = &Ds[rbase * 32];
    }

    int aoff[4], boff[4];
#pragma unroll
    for (int mi = 0; mi < 4; mi++) {
        int r = wm + mi * 16 + l15;
        aoff[mi] = r * 32 + (lq ^ ((r >> 1) & 3)) * 8;
    }
#pragma unroll
    for (int ni = 0; ni < 4; ni++) {
        int r = wn + ni * 16 + l15;
        boff[ni] = r * 32 + (lq ^ ((r >> 1) & 3)) * 8;
    }

    f32x4 c[4][4];
#pragma unroll
    for (int i = 0; i < 4; i++)
#pragma unroll
        for (int j = 0; j < 4; j++) c[i][j] = (f32x4)0.f;

    for (int k0 = 0; k0 < FFN / 2; k0 += 32) {
#pragma unroll
        for (int j = 0; j < 2; j++) {
            gl_lds16(hsrc[j] + k0, hdst[j]);
            gl_lds16(dsrc[j] + k0, ddst[j]);
        }
        __syncthreads();
        short8 af[4], bd[4];
#pragma unroll
        for (int mi = 0; mi < 4; mi++) af[mi] = *(const short8*)&Hs[aoff[mi]];
#pragma unroll
        for (int ni = 0; ni < 4; ni++) bd[ni] = *(const short8*)&Ds[boff[ni]];
#pragma unroll
        for (int mi = 0; mi < 4; mi++)
#pragma unroll
            for (int ni = 0; ni < 4; ni++)
                c[mi][ni] = __builtin_amdgcn_mfma_f32_16x16x32_bf16(af[mi], bd[ni], c[mi][ni], 0, 0, 0);
        __syncthreads();
    }

#pragma unroll
    for (int mi = 0; mi < 4; mi++)
#pragma unroll
        for (int r = 0; r < 4; r++) {
            int row = wm + mi * 16 + lq * 4 + r;
            int grow = row0 + row;
            if (grow < cnt) {
                int t = stok[row];
                float wgt = swt[row];
                float* orow = out + (size_t)t * HIDDEN + h0 + wn;
#pragma unroll
                for (int ni = 0; ni < 4; ni++)
                    atomicAdd(&orow[ni * 16 + l15], wgt * c[mi][ni][r]);
            }
        }
}

// ================= Fallback path (R2 kernels, used if ws too small) ============
#define LDW 40
__global__ void __launch_bounds__(256, 2)
ffn1_fb(const float* __restrict__ x, const float* __restrict__ Wg,
        const float* __restrict__ Wu, const int* __restrict__ counts,
        const int* __restrict__ tok, __hip_bfloat16* __restrict__ hbuf)
{
    int e = blockIdx.z;
    int cnt = counts[e];
    int row0 = blockIdx.x * 128;
    if (row0 >= cnt) return;
    int off_e = 0;
#pragma unroll
    for (int i = 0; i < NEXP; i++) if (i < e) off_e += counts[i];
    int f0 = blockIdx.y * 64;

    __shared__ short Xs[128][LDW];
    __shared__ short Gs[64][LDW];
    __shared__ short Us[64][LDW];
    __shared__ int   stok[128];

    int tid = threadIdx.x;
    if (tid < 128) stok[tid] = tok[e * NTOK + min(row0 + tid, cnt - 1)];
    __syncthreads();

    int lane = tid & 63, w = tid >> 6;
    int wm = (w & 1) * 64, wn = (w >> 1) * 32;
    int l15 = lane & 15, lq = lane >> 4;

    f32x4 cg[4][2], cu[4][2];
#pragma unroll
    for (int i = 0; i < 4; i++)
#pragma unroll
        for (int j = 0; j < 2; j++) { cg[i][j] = (f32x4)0.f; cu[i][j] = (f32x4)0.f; }

    const float* Wge = Wg + (size_t)e * FFN * HIDDEN;
    const float* Wue = Wu + (size_t)e * FFN * HIDDEN;

    int xr[4], xc[4]; const float* xp[4];
#pragma unroll
    for (int i = 0; i < 4; i++) {
        int idx = tid + 256 * i;
        xr[i] = idx >> 3; xc[i] = (idx & 7) * 4;
        xp[i] = x + (size_t)stok[xr[i]] * HIDDEN + xc[i];
    }
    int wr[2], wc[2]; const float* gp[2]; const float* up[2];
#pragma unroll
    for (int i = 0; i < 2; i++) {
        int idx = tid + 256 * i;
        wr[i] = idx >> 3; wc[i] = (idx & 7) * 4;
        gp[i] = Wge + (size_t)(f0 + wr[i]) * HIDDEN + wc[i];
        up[i] = Wue + (size_t)(f0 + wr[i]) * HIDDEN + wc[i];
    }

    float4 xa[4], ga[2], ua[2];
#pragma unroll
    for (int i = 0; i < 4; i++) xa[i] = *(const float4*)(xp[i]);
#pragma unroll
    for (int i = 0; i < 2; i++) { ga[i] = *(const float4*)(gp[i]); ua[i] = *(const float4*)(up[i]); }

    for (int k0 = 0; k0 < HIDDEN; k0 += 32) {
        __syncthreads();
#pragma unroll
        for (int i = 0; i < 4; i++) {
            short* d = &Xs[xr[i]][xc[i]];
            d[0] = f2bf(xa[i].x); d[1] = f2bf(xa[i].y);
            d[2] = f2bf(xa[i].z); d[3] = f2bf(xa[i].w);
        }
#pragma unroll
        for (int i = 0; i < 2; i++) {
            short* d = &Gs[wr[i]][wc[i]];
            d[0] = f2bf(ga[i].x); d[1] = f2bf(ga[i].y);
            d[2] = f2bf(ga[i].z); d[3] = f2bf(ga[i].w);
            short* d2 = &Us[wr[i]][wc[i]];
            d2[0] = f2bf(ua[i].x); d2[1] = f2bf(ua[i].y);
            d2[2] = f2bf(ua[i].z); d2[3] = f2bf(ua[i].w);
        }
        __syncthreads();
        if (k0 + 32 < HIDDEN) {
            int kn = k0 + 32;
#pragma unroll
            for (int i = 0; i < 4; i++) xa[i] = *(const float4*)(xp[i] + kn);
#pragma unroll
            for (int i = 0; i < 2; i++) { ga[i] = *(const float4*)(gp[i] + kn); ua[i] = *(const float4*)(up[i] + kn); }
        }
        short8 af[4], bg[2], bu[2];
#pragma unroll
        for (int mi = 0; mi < 4; mi++) af[mi] = *(const short8*)&Xs[wm + mi * 16 + l15][lq * 8];
#pragma unroll
        for (int ni = 0; ni < 2; ni++) {
            bg[ni] = *(const short8*)&Gs[wn + ni * 16 + l15][lq * 8];
            bu[ni] = *(const short8*)&Us[wn + ni * 16 + l15][lq * 8];
        }
#pragma unroll
        for (int mi = 0; mi < 4; mi++)
#pragma unroll
            for (int ni = 0; ni < 2; ni++) {
                cg[mi][ni] = __builtin_amdgcn_mfma_f32_16x16x32_bf16(af[mi], bg[ni], cg[mi][ni], 0, 0, 0);
                cu[mi][ni] = __builtin_amdgcn_mfma_f32_16x16x32_bf16(af[mi], bu[ni], cu[mi][ni], 0, 0, 0);
            }
    }

#pragma unroll
    for (int mi = 0; mi < 4; mi++)
#pragma unroll
        for (int r = 0; r < 4; r++) {
            int row = wm + mi * 16 + lq * 4 + r;
            int grow = row0 + row;
            if (grow < cnt) {
                __hip_bfloat16* hrow = hbuf + (size_t)(off_e + grow) * FFN + f0 + wn;
#pragma unroll
                for (int ni = 0; ni < 2; ni++) {
                    float g = cg[mi][ni][r], u = cu[mi][ni][r];
                    float h = g / (1.f + __expf(-g)) * u;
                    hrow[ni * 16 + l15] = __float2bfloat16(h);
                }
            }
        }
}

__global__ void __launch_bounds__(256, 2)
ffn2_fb(const __hip_bfloat16* __restrict__ hbuf, const float* __restrict__ Wd,
        const int* __restrict__ counts, const int* __restrict__ tok,
        const float* __restrict__ wts, float* __restrict__ out)
{
    int e = blockIdx.z;
    int cnt = counts[e];
    int row0 = blockIdx.x * 128;
    if (row0 >= cnt) return;
    int off_e = 0;
#pragma unroll
    for (int i = 0; i < NEXP; i++) if (i < e) off_e += counts[i];
    int h0 = blockIdx.y * 64;

    __shared__ short Hs[128][LDW];
    __shared__ short Ds[64][LDW];
    __shared__ int   stok[128];
    __shared__ float swt[128];

    int tid = threadIdx.x;
    if (tid < 128) {
        int rc = min(row0 + tid, cnt - 1);
        stok[tid] = tok[e * NTOK + rc];
        swt[tid]  = wts[e * NTOK + rc];
    }
    __syncthreads();

    int lane = tid & 63, w = tid >> 6;
    int wm = (w & 1) * 64, wn = (w >> 1) * 32;
    int l15 = lane & 15, lq = lane >> 4;

    f32x4 c[4][2];
#pragma unroll
    for (int i = 0; i < 4; i++)
#pragma unroll
        for (int j = 0; j < 2; j++) c[i][j] = (f32x4)0.f;

    const float* Wde = Wd + (size_t)e * HIDDEN * FFN;

    int hr[2], hc[2]; const short* hp[2];
#pragma unroll
    for (int i = 0; i < 2; i++) {
        int idx = tid + 256 * i;
        hr[i] = idx >> 2; hc[i] = (idx & 3) * 8;
        int ar = min(row0 + hr[i], cnt - 1);
        hp[i] = (const short*)(hbuf + (size_t)(off_e + ar) * FFN + hc[i]);
    }
    int dr[2], dc[2]; const float* dp[2];
#pragma unroll
    for (int i = 0; i < 2; i++) {
        int idx = tid + 256 * i;
        dr[i] = idx >> 3; dc[i] = (idx & 7) * 4;
        dp[i] = Wde + (size_t)(h0 + dr[i]) * FFN + dc[i];
    }

    short8 ha[2]; float4 da[2];
#pragma unroll
    for (int i = 0; i < 2; i++) { ha[i] = *(const short8*)(hp[i]); da[i] = *(const float4*)(dp[i]); }

    for (int k0 = 0; k0 < FFN; k0 += 32) {
        __syncthreads();
#pragma unroll
        for (int i = 0; i < 2; i++) {
            *(short8*)&Hs[hr[i]][hc[i]] = ha[i];
            short* d = &Ds[dr[i]][dc[i]];
            d[0] = f2bf(da[i].x); d[1] = f2bf(da[i].y);
            d[2] = f2bf(da[i].z); d[3] = f2bf(da[i].w);
        }
        __syncthreads();
        if (k0 + 32 < FFN) {
            int kn = k0 + 32;
#pragma unroll
            for (int i = 0; i < 2; i++) { ha[i] = *(const short8*)(hp[i] + kn); da[i] = *(const float4*)(dp[i] + kn); }
        }
        short8 af[4], bf_[2];
#pragma unroll
        for (int mi = 0; mi < 4; mi++) af[mi] = *(const short8*)&Hs[wm + mi * 16 + l15][lq * 8];
#pragma unroll
        for (int ni = 0; ni < 2; ni++) bf_[ni] = *(const short8*)&Ds[wn + ni * 16 + l15][lq * 8];
#pragma unroll
        for (int mi = 0; mi < 4; mi++)
#pragma unroll
            for (int ni = 0; ni < 2; ni++)
                c[mi][ni] = __builtin_amdgcn_mfma_f32_16x16x32_bf16(af[mi], bf_[ni], c[mi][ni], 0, 0, 0);
    }

#pragma unroll
    for (int mi = 0; mi < 4; mi++)
#pragma unroll
        for (int r = 0; r < 4; r++) {
            int row = wm + mi * 16 + lq * 4 + r;
            int grow = row0 + row;
            if (grow < cnt) {
                int t = stok[row];
                float wgt = swt[row];
                float* orow = out + (size_t)t * HIDDEN + h0 + wn;
#pragma unroll
                for (int ni = 0; ni < 2; ni++)
                    atomicAdd(&orow[ni * 16 + l15], wgt * c[mi][ni][r]);
            }
        }
}

extern "C" void kernel_launch(void* const* d_in, const int* in_sizes, int n_in,
                              void* d_out, int out_size, void* d_ws, size_t ws_size,
                              hipStream_t stream) {
    const float* x     = (const float*)d_in[0];
    const float* Wgate = (const float*)d_in[1];
    const float* Wg    = (const float*)d_in[2];
    const float* Wu    = (const float*)d_in[3];
    const float* Wd    = (const float*)d_in[4];
    float* out = (float*)d_out;

    char* ws = (char*)d_ws;
    int*   counts = (int*)ws;
    int*   tok    = (int*)(ws + 256);
    float* wts    = (float*)(ws + 256 + NEXP * NTOK * 4);

    hipMemsetAsync(counts, 0, 256, stream);
    hipMemsetAsync(out, 0, (size_t)out_size * sizeof(float), stream);

    router_kernel<<<NTOK, 64, 0, stream>>>(x, Wgate, counts, tok, wts);

    const size_t base = 256 + 2 * (size_t)NEXP * NTOK * 4;   // 131328
    const size_t NEED = base
        + 2ull * NTOK * HIDDEN                // xbf
        + 3ull * 2ull * NEXP * FFN * HIDDEN   // Wg/Wu/Wd bf16
        + 2ull * 2ull * NTOK * FFN;           // hbuf (4096 x 2816)

    if (ws_size >= NEED) {
        short* xbf  = (short*)(ws + base);
        short* wgbf = xbf  + (size_t)NTOK * HIDDEN;
        short* wubf = wgbf + (size_t)NEXP * FFN * HIDDEN;
        short* wdbf = wubf + (size_t)NEXP * FFN * HIDDEN;
        short* hbuf = wdbf + (size_t)NEXP * HIDDEN * FFN;

        cvt_all<<<8192, 256, 0, stream>>>(x, Wg, Wu, Wd, xbf, wgbf, wubf, wdbf);

        dim3 g1(NTOK / 128, FFN / 128, NEXP);        // 16 x 22 x 8, early-exit
        ffn1_v3<<<g1, 256, 0, stream>>>(xbf, wgbf, wubf, counts, tok, hbuf);

        dim3 g2(NTOK / 128, (HIDDEN / 128) * 2, NEXP); // 16 x 16 x 8 (K split 2)
        ffn2_v3<<<g2, 256, 0, stream>>>(hbuf, wdbf, counts, tok, wts, out);
    } else {
        __hip_bfloat16* hbuf = (__hip_bfloat16*)(ws + base);
        dim3 g1(NTOK / 128, FFN / 64, NEXP);
        ffn1_fb<<<g1, 256, 0, stream>>>(x, Wg, Wu, counts, tok, hbuf);
        dim3 g2(NTOK / 128, HIDDEN / 64, NEXP);
        ffn2_fb<<<g2, 256, 0, stream>>>(hbuf, Wd, counts, tok, wts, out);
    }
}